// Round 13
// baseline (338.750 us; speedup 1.0000x reference)
//
#include <hip/hip_runtime.h>
#include <cstdint>
#include <cstddef>

typedef __attribute__((ext_vector_type(8))) short bf16x8;
typedef __attribute__((ext_vector_type(4))) float f32x4;
typedef unsigned short u16;

#define H1_ROW_B   1920                 /* packed row: 30x * 32ci * 2B     */
#define H1_BATCH   (30 * 30 * 960)      /* elems per batch (864000)        */
#define LDS_STRIDE 1952                 /* 1920 + 32: 488 dw = 8-bank row shift */
#define B_LDS_OFF  (36 * LDS_STRIDE)    /* 70272: B double buffer          */
#define OUT_CSTR   21952                /* 28*28*28                        */

__device__ __forceinline__ u16 f2bf(float f) {
    union { float f; unsigned u; } v; v.f = f;
    unsigned r = v.u + 0x7FFF + ((v.u >> 16) & 1);   // RNE
    return (u16)(r >> 16);
}

__device__ __forceinline__ void fma4(float4& a, float s, const float4& w) {
    a.x = fmaf(s, w.x, a.x);
    a.y = fmaf(s, w.y, a.y);
    a.z = fmaf(s, w.z, a.z);
    a.w = fmaf(s, w.w, a.w);
}

__device__ __forceinline__ void gld_lds(const char* src, unsigned char* dst) {
    __builtin_amdgcn_global_load_lds(
        (const __attribute__((address_space(1))) void*)src,
        (__attribute__((address_space(3))) void*)dst, 16, 0, 0);
}

// ---------------- conv1 + bias + relu -> bf16 h1 [bl][z][y][30x][32ci] ----
__global__ __launch_bounds__(256) void conv1_relu(
    const float* __restrict__ x, const float* __restrict__ w1,
    const float* __restrict__ b1, u16* __restrict__ h1, int b0)
{
    __shared__ float wl[27 * 32 + 32];

    const int z   = blockIdx.x;        // 0..29
    const int yt  = blockIdx.y;        // 0..4
    const int bl  = blockIdx.z;
    const int b   = b0 + bl;
    const int tid = threadIdx.x;

    for (int i = tid; i < 27 * 32; i += 256) wl[i] = w1[i];
    if (tid < 32) wl[27 * 32 + tid] = b1[tid];
    __syncthreads();

    const int c4   = tid & 7;          // ci c4*4 .. +3
    const int slot = tid >> 3;         // 0..31; active slots 0..29

    const float4 bias = *reinterpret_cast<const float4*>(&wl[27 * 32 + c4 * 4]);
    const float* xb  = x + (size_t)b * 32768;
    u16*         h1b = h1 + (size_t)bl * H1_BATCH;

    if (slot < 30) {
#pragma unroll 1
        for (int j = 0; j < 3; ++j) {
            const int p  = slot + 30 * j;     // 0..89 pair index
            const int yy = p / 15;
            const int xx = (p - yy * 15) * 2; // 0,2,..,28 (8B aligned)
            const int y  = yt * 6 + yy;

            float4 acc0 = bias, acc1 = bias;
#pragma unroll
            for (int kd = 0; kd < 3; ++kd) {
#pragma unroll
                for (int kh = 0; kh < 3; ++kh) {
                    const float* row = xb + ((size_t)(z + kd) * 32 + (y + kh)) * 32 + xx;
                    const float2 v01 = *reinterpret_cast<const float2*>(row);
                    const float2 v23 = *reinterpret_cast<const float2*>(row + 2);
                    const int t = (kd * 3 + kh) * 3;
                    const float4 w0  = *reinterpret_cast<const float4*>(&wl[(t + 0) * 32 + c4 * 4]);
                    const float4 w1v = *reinterpret_cast<const float4*>(&wl[(t + 1) * 32 + c4 * 4]);
                    const float4 w2v = *reinterpret_cast<const float4*>(&wl[(t + 2) * 32 + c4 * 4]);
                    fma4(acc0, v01.x, w0);
                    fma4(acc0, v01.y, w1v);
                    fma4(acc0, v23.x, w2v);
                    fma4(acc1, v01.y, w0);
                    fma4(acc1, v23.x, w1v);
                    fma4(acc1, v23.y, w2v);
                }
            }
            ushort4 s0, s1;
            s0.x = f2bf(fmaxf(acc0.x, 0.f)); s0.y = f2bf(fmaxf(acc0.y, 0.f));
            s0.z = f2bf(fmaxf(acc0.z, 0.f)); s0.w = f2bf(fmaxf(acc0.w, 0.f));
            s1.x = f2bf(fmaxf(acc1.x, 0.f)); s1.y = f2bf(fmaxf(acc1.y, 0.f));
            s1.z = f2bf(fmaxf(acc1.z, 0.f)); s1.w = f2bf(fmaxf(acc1.w, 0.f));
            u16* dst = h1b + ((size_t)(z * 30 + y) * 30 + xx) * 32 + c4 * 4;
            *reinterpret_cast<ushort4*>(dst)      = s0;
            *reinterpret_cast<ushort4*>(dst + 32) = s1;
        }
    }
}

// ---------------- pack w2 fp32 DHWIO -> bf16 B-fragments ------------------
__global__ __launch_bounds__(256) void pack_w2(
    const float* __restrict__ w2, u16* __restrict__ wB)
{
    const int tap = blockIdx.x;      // 0..26
    const int tid = threadIdx.x;
    const int nt = tid >> 6;
    const int l  = tid & 63;
    const int r = l & 15, q = l >> 4;
    u16* dst = wB + ((size_t)(tap * 4 + nt) * 64 + l) * 8;
#pragma unroll
    for (int j = 0; j < 8; ++j)
        dst[j] = f2bf(w2[(size_t)(tap * 32 + q * 8 + j) * 64 + nt * 16 + r]);
}

// ---------------- conv2: 54-phase interleaved MFMA pipeline ---------------
// r12 geometry (8 waves, A 36x1920 LDS, B 2x4KB LDS dbuf), restructured per
// the T3/T4 phase recipe: 2 phases per tap, operands read one phase before
// use, RAW s_barrier (no vmcnt drain) + sched_barrier pins, rotating stager
// with counted-slack vmcnt(0) a full tap after issue.
//   phase (t,0): read A(t)+B23(t) | MFMA nt01(t) [A same-phase, B01 prefetched]
//                | stager(t+1) vmcnt(0) | barrier
//   phase (t,1): read B01(t+1)    | MFMA nt23(t) [A,B23 prefetched]
//                | stager issues B(t+2) | barrier
// Staging protocol: B(0) pre-barrier wave0; B(1) post-barrier wave1;
// B(t+2) issued at (t,1) by wave (t+2)&7 into buf[(t+2)&1] (last read (t,0),
// barrier-separated); its vmcnt(0) at (t+1,0) => ~1 tap slack, no stall.
template<int NMT, int XOUT>
__device__ __forceinline__ void conv2_body(
    const unsigned char* smem, const char* wBb,
    const float* __restrict__ b2, float* __restrict__ out,
    int b, int y0, int z0, int zw, int wv, int l)
{
    const int r = l & 15, q = l >> 4;
    const int yl = r >> 2, xg = r & 3;

    f32x4 acc[NMT][4];
#pragma unroll
    for (int nt = 0; nt < 4; ++nt) {
        const float bv = b2[nt * 16 + r];
        const f32x4 bi = {bv, bv, bv, bv};
#pragma unroll
        for (int mt = 0; mt < NMT; ++mt) acc[mt][nt] = bi;
    }

    const unsigned char* aBase =
        smem + (zw * 6 + yl) * LDS_STRIDE + (XOUT + xg) * 64 + q * 16;
    const unsigned char* bBase = smem + B_LDS_OFF + (size_t)l * 16;

    // prologue reads: B01(0) from buf0 (A(0) read in phase (0,0))
    bf16x8 B01a = *reinterpret_cast<const bf16x8*>(bBase);
    bf16x8 B01b = *reinterpret_cast<const bf16x8*>(bBase + 1024);
    bf16x8 A_cur[NMT];
    bf16x8 B23a, B23b;

#pragma unroll
    for (int tap = 0; tap < 27; ++tap) {
        const int kd = tap / 9;
        const int kh = (tap - kd * 9) / 3;
        const int kw = tap - kd * 9 - kh * 3;
        const unsigned char* ap = aBase + (kd * 6 + kh) * LDS_STRIDE + kw * 64;
        const unsigned char* bb = bBase + (tap & 1) * 4096;

        // ================= phase (t,0) =================
#pragma unroll
        for (int mt = 0; mt < NMT; ++mt)
            A_cur[mt] = *reinterpret_cast<const bf16x8*>(ap + mt * 256);
        B23a = *reinterpret_cast<const bf16x8*>(bb + 2048);
        B23b = *reinterpret_cast<const bf16x8*>(bb + 3072);

        __builtin_amdgcn_s_setprio(1);
#pragma unroll
        for (int mt = 0; mt < NMT; ++mt) {
            acc[mt][0] = __builtin_amdgcn_mfma_f32_16x16x32_bf16(A_cur[mt], B01a, acc[mt][0], 0, 0, 0);
            acc[mt][1] = __builtin_amdgcn_mfma_f32_16x16x32_bf16(A_cur[mt], B01b, acc[mt][1], 0, 0, 0);
        }
        __builtin_amdgcn_s_setprio(0);

        // stager of B(t+1) (issued at (t-1,1) or prologue): ensure landed
        if (tap < 26 && wv == ((tap + 1) & 7))
            asm volatile("s_waitcnt vmcnt(0)");

        __builtin_amdgcn_sched_barrier(0);
        __builtin_amdgcn_s_barrier();      // publishes B(t+1)
        __builtin_amdgcn_sched_barrier(0);

        // ================= phase (t,1) =================
        if (tap < 26) {
            const unsigned char* bn = bBase + ((tap + 1) & 1) * 4096;
            B01a = *reinterpret_cast<const bf16x8*>(bn);
            B01b = *reinterpret_cast<const bf16x8*>(bn + 1024);
        }
        // stager issues B(t+2) into buf[(t+2)&1] (free since (t,0) barrier)
        if (tap < 25 && wv == ((tap + 2) & 7)) {
            const char* bsrc = wBb + (size_t)(tap + 2) * 4096 + l * 16;
            unsigned char* bdst = const_cast<unsigned char*>(smem)
                + B_LDS_OFF + ((tap + 2) & 1) * 4096 + l * 16;
#pragma unroll
            for (int k = 0; k < 4; ++k)
                gld_lds(bsrc + k * 1024, bdst + k * 1024);
        }

        __builtin_amdgcn_s_setprio(1);
#pragma unroll
        for (int mt = 0; mt < NMT; ++mt) {
            acc[mt][2] = __builtin_amdgcn_mfma_f32_16x16x32_bf16(A_cur[mt], B23a, acc[mt][2], 0, 0, 0);
            acc[mt][3] = __builtin_amdgcn_mfma_f32_16x16x32_bf16(A_cur[mt], B23b, acc[mt][3], 0, 0, 0);
        }
        __builtin_amdgcn_s_setprio(0);

        __builtin_amdgcn_sched_barrier(0);
        __builtin_amdgcn_s_barrier();
        __builtin_amdgcn_sched_barrier(0);
    }

    // epilogue: lane (r,q): co = nt*16+r, y = y0+q, x = XOUT+mt*4 (+j contig)
    const int z = z0 + zw;
    float* ob = out + ((size_t)b * 64 + r) * OUT_CSTR
                    + (size_t)z * 784 + (size_t)(y0 + q) * 28 + XOUT;
#pragma unroll
    for (int mt = 0; mt < NMT; ++mt) {
#pragma unroll
        for (int nt = 0; nt < 4; ++nt) {
            const f32x4 v = acc[mt][nt];
            float4 st;
            st.x = fmaxf(v.x, 0.f);
            st.y = fmaxf(v.y, 0.f);
            st.z = fmaxf(v.z, 0.f);
            st.w = fmaxf(v.w, 0.f);
            *reinterpret_cast<float4*>(ob + (size_t)nt * 16 * OUT_CSTR + mt * 4) = st;
        }
    }
}

__global__ __launch_bounds__(512, 4) void conv2_mfma(
    const u16* __restrict__ h1, const u16* __restrict__ wB,
    const float* __restrict__ b2, float* __restrict__ out, int b0)
{
    __shared__ __align__(16) unsigned char smem[B_LDS_OFF + 8192];  // 78464 B

    const int g   = gridDim.x;
    const int bid = blockIdx.x;
    const int lb  = (g % 8 == 0) ? ((bid & 7) * (g >> 3) + (bid >> 3)) : bid;

    const int t0  = lb % 49;
    const int bl  = lb / 49;
    const int yg  = t0 % 7;
    const int zt  = t0 / 7;

    const int b  = b0 + bl;
    const int y0 = yg * 4, z0 = zt * 4;
    const int tid = threadIdx.x;
    const int wv  = tid >> 6;       // 0..7
    const int l   = tid & 63;
    const int zw  = wv >> 1;        // z-plane offset 0..3
    const int xh  = wv & 1;         // x-half

    const char* wBb = (const char*)wB;

    // ---- stage A: 36 rows x 1920 B, chunks at 0 and 896 (128 B overlap) --
    {
        const char* gbase = (const char*)(h1 + (size_t)bl * H1_BATCH);
        for (int c = wv; c < 72; c += 8) {           // wave-uniform chunks
            const int rid = c >> 1, half = c & 1;
            const int zz = rid / 6, yy = rid - zz * 6;
            const char* src = gbase
                + (size_t)((z0 + zz) * 30 + (y0 + yy)) * H1_ROW_B
                + half * 896 + l * 16;
            unsigned char* dst = smem + rid * LDS_STRIDE + half * 896 + l * 16;
            gld_lds(src, dst);
        }
    }
    // ---- stage B(0) into buf 0 (wave 0, drained by the barrier) ----
    if (wv == 0) {
        const char* bsrc = wBb + l * 16;
        unsigned char* bdst = smem + B_LDS_OFF + l * 16;
#pragma unroll
        for (int k = 0; k < 4; ++k)
            gld_lds(bsrc + k * 1024, bdst + k * 1024);
    }
    __syncthreads();   // full drain: A + B(0) ready

    // ---- issue B(1) into buf 1 (wave 1; vmcnt(0) at phase (0,0)) ----
    if (wv == 1) {
        const char* bsrc = wBb + 4096 + l * 16;
        unsigned char* bdst = smem + B_LDS_OFF + 4096 + l * 16;
#pragma unroll
        for (int k = 0; k < 4; ++k)
            gld_lds(bsrc + k * 1024, bdst + k * 1024);
    }

    if (xh == 0)
        conv2_body<4, 0>(smem, wBb, b2, out, b, y0, z0, zw, wv, l);
    else
        conv2_body<3, 16>(smem, wBb, b2, out, b, y0, z0, zw, wv, l);
}

extern "C" void kernel_launch(void* const* d_in, const int* in_sizes, int n_in,
                              void* d_out, int out_size, void* d_ws, size_t ws_size,
                              hipStream_t stream)
{
    const float* x  = (const float*)d_in[0];
    const float* w1 = (const float*)d_in[1];
    const float* b1 = (const float*)d_in[2];
    const float* w2 = (const float*)d_in[3];
    const float* b2 = (const float*)d_in[4];
    float* out = (float*)d_out;

    u16* wB = (u16*)d_ws;                               // 110,592 B packed weights
    u16* h1 = (u16*)((char*)d_ws + 131072);

    pack_w2<<<27, 256, 0, stream>>>(w2, wB);

    const size_t per_batch = (size_t)H1_BATCH * 2;      // 1,728,000 B
    size_t avail = ws_size > 131072 ? ws_size - 131072 : 0;
    int bchunk = (int)(avail / per_batch);
    if (bchunk < 1)  bchunk = 1;
    if (bchunk > 64) bchunk = 64;

    for (int b0 = 0; b0 < 64; b0 += bchunk) {
        int bc = 64 - b0;
        if (bc > bchunk) bc = bchunk;
        conv1_relu<<<dim3(30, 5, bc), 256, 0, stream>>>(x, w1, b1, h1, b0);
        conv2_mfma<<<dim3(49 * bc), 512, 0, stream>>>(h1, wB, b2, out, b0);
    }
}

// Round 14
// 271.967 us; speedup vs baseline: 1.2456x; 1.2456x over previous
//
#include <hip/hip_runtime.h>
#include <cstdint>
#include <cstddef>

typedef __attribute__((ext_vector_type(8))) short bf16x8;
typedef __attribute__((ext_vector_type(4))) float f32x4;
typedef __attribute__((ext_vector_type(4))) unsigned int u32x4;
typedef unsigned short u16;

#define H1_ROW_B   1920                 /* packed row: 30x * 32ci * 2B     */
#define H1_BATCH   (30 * 30 * 960)      /* elems per batch (864000)        */
#define LDS_STRIDE 1952                 /* 1920 + 32: 488 dw = 8-bank row shift */
#define OUT_CSTR   21952                /* 28*28*28                        */

__device__ __forceinline__ u16 f2bf(float f) {
    union { float f; unsigned u; } v; v.f = f;
    unsigned r = v.u + 0x7FFF + ((v.u >> 16) & 1);   // RNE
    return (u16)(r >> 16);
}

__device__ __forceinline__ void fma4(float4& a, float s, const float4& w) {
    a.x = fmaf(s, w.x, a.x);
    a.y = fmaf(s, w.y, a.y);
    a.z = fmaf(s, w.z, a.z);
    a.w = fmaf(s, w.w, a.w);
}

__device__ __forceinline__ void gld_lds(const char* src, unsigned char* dst) {
    __builtin_amdgcn_global_load_lds(
        (const __attribute__((address_space(1))) void*)src,
        (__attribute__((address_space(3))) void*)dst, 16, 0, 0);
}

// ---------------- conv1 + bias + relu -> bf16 h1 [bl][z][y][30x][32ci] ----
// x-pair register blocking: 2 sites/thread share 9 aligned float2 row loads.
__global__ __launch_bounds__(256) void conv1_relu(
    const float* __restrict__ x, const float* __restrict__ w1,
    const float* __restrict__ b1, u16* __restrict__ h1, int b0)
{
    __shared__ float wl[27 * 32 + 32];

    const int z   = blockIdx.x;        // 0..29
    const int yt  = blockIdx.y;        // 0..4
    const int bl  = blockIdx.z;
    const int b   = b0 + bl;
    const int tid = threadIdx.x;

    for (int i = tid; i < 27 * 32; i += 256) wl[i] = w1[i];
    if (tid < 32) wl[27 * 32 + tid] = b1[tid];
    __syncthreads();

    const int c4   = tid & 7;          // ci c4*4 .. +3
    const int slot = tid >> 3;         // 0..31; active slots 0..29

    const float4 bias = *reinterpret_cast<const float4*>(&wl[27 * 32 + c4 * 4]);
    const float* xb  = x + (size_t)b * 32768;
    u16*         h1b = h1 + (size_t)bl * H1_BATCH;

    if (slot < 30) {
#pragma unroll 1
        for (int j = 0; j < 3; ++j) {
            const int p  = slot + 30 * j;     // 0..89 pair index
            const int yy = p / 15;
            const int xx = (p - yy * 15) * 2; // 0,2,..,28 (8B aligned)
            const int y  = yt * 6 + yy;

            float4 acc0 = bias, acc1 = bias;
#pragma unroll
            for (int kd = 0; kd < 3; ++kd) {
#pragma unroll
                for (int kh = 0; kh < 3; ++kh) {
                    const float* row = xb + ((size_t)(z + kd) * 32 + (y + kh)) * 32 + xx;
                    const float2 v01 = *reinterpret_cast<const float2*>(row);
                    const float2 v23 = *reinterpret_cast<const float2*>(row + 2);
                    const int t = (kd * 3 + kh) * 3;
                    const float4 w0  = *reinterpret_cast<const float4*>(&wl[(t + 0) * 32 + c4 * 4]);
                    const float4 w1v = *reinterpret_cast<const float4*>(&wl[(t + 1) * 32 + c4 * 4]);
                    const float4 w2v = *reinterpret_cast<const float4*>(&wl[(t + 2) * 32 + c4 * 4]);
                    fma4(acc0, v01.x, w0);
                    fma4(acc0, v01.y, w1v);
                    fma4(acc0, v23.x, w2v);
                    fma4(acc1, v01.y, w0);
                    fma4(acc1, v23.x, w1v);
                    fma4(acc1, v23.y, w2v);
                }
            }
            ushort4 s0, s1;
            s0.x = f2bf(fmaxf(acc0.x, 0.f)); s0.y = f2bf(fmaxf(acc0.y, 0.f));
            s0.z = f2bf(fmaxf(acc0.z, 0.f)); s0.w = f2bf(fmaxf(acc0.w, 0.f));
            s1.x = f2bf(fmaxf(acc1.x, 0.f)); s1.y = f2bf(fmaxf(acc1.y, 0.f));
            s1.z = f2bf(fmaxf(acc1.z, 0.f)); s1.w = f2bf(fmaxf(acc1.w, 0.f));
            u16* dst = h1b + ((size_t)(z * 30 + y) * 30 + xx) * 32 + c4 * 4;
            *reinterpret_cast<ushort4*>(dst)      = s0;
            *reinterpret_cast<ushort4*>(dst + 32) = s1;
        }
    }
}

// ---------------- pack w2 fp32 DHWIO -> bf16 B-fragments ------------------
// wB[((tap*4 + nt)*64 + lane)*8 + j] = bf16(w2[tap][(lane>>4)*8 + j][nt*16 + (lane&15)])
__global__ __launch_bounds__(256) void pack_w2(
    const float* __restrict__ w2, u16* __restrict__ wB)
{
    const int tap = blockIdx.x;      // 0..26
    const int tid = threadIdx.x;
    const int nt = tid >> 6;
    const int l  = tid & 63;
    const int r = l & 15, q = l >> 4;
    u16* dst = wB + ((size_t)(tap * 4 + nt) * 64 + l) * 8;
#pragma unroll
    for (int j = 0; j < 8; ++j)
        dst[j] = f2bf(w2[(size_t)(tap * 32 + q * 8 + j) * 64 + nt * 16 + r]);
}

// ---------------- conv2 implicit-GEMM MFMA, 8-wave N-split (r9 config) ----
// Grid 49*bc x 512 thr (XCD-swizzled when %8==0). Block: 4z x 4y x 28x.
// 8 waves: wave wv -> z-plane zw=wv>>1, N-half nh=wv&1 (co nh*32..+31).
// Per wave: 7 m-tiles x 2 n-frags (14 MFMA/tap — short serial chain that
// interleaves well at 4 waves/SIMD; best measured config, r9).
// A in LDS: 36 rows x 1920 B, stride 1952 (verified 0-conflict).
// B from global, 2 KB/wave/tap, **2-deep prefetch** (3 slots, vmcnt(4):
// taps t+1,t+2 stay in flight => B L2-latency structurally covered).
// No setprio (m190: hurts lockstep GEMM). 2 blocks/CU, 16 waves/CU.
__global__ __launch_bounds__(512, 4) void conv2_mfma(
    const u16* __restrict__ h1, const u16* __restrict__ wB,
    const float* __restrict__ b2, float* __restrict__ out, int b0)
{
    __shared__ __align__(16) unsigned char smem[36 * LDS_STRIDE];  // 70272 B

    const int g   = gridDim.x;
    const int bid = blockIdx.x;
    const int lb  = (g % 8 == 0) ? ((bid & 7) * (g >> 3) + (bid >> 3)) : bid;

    const int t0  = lb % 49;
    const int bl  = lb / 49;
    const int yg  = t0 % 7;
    const int zt  = t0 / 7;

    const int b  = b0 + bl;
    const int y0 = yg * 4, z0 = zt * 4;
    const int tid = threadIdx.x;
    const int wv  = tid >> 6;       // 0..7
    const int l   = tid & 63;
    const int zw  = wv >> 1;        // wave z offset 0..3
    const int nh  = wv & 1;         // wave N half
    const int r = l & 15, q = l >> 4;
    const int yl = r >> 2, xg = r & 3;

    const char* wBl = (const char*)wB + nh * 2048 + l * 16;

    // ---- stage A: 36 rows x 1920 B, chunks at 0 and 896 (128 B overlap) --
    {
        const char* gbase = (const char*)(h1 + (size_t)bl * H1_BATCH);
        for (int c = wv; c < 72; c += 8) {           // wave-uniform chunks
            const int rid = c >> 1, half = c & 1;
            const int zz = rid / 6, yy = rid - zz * 6;
            const char* src = gbase
                + (size_t)((z0 + zz) * 30 + (y0 + yy)) * H1_ROW_B
                + half * 896 + l * 16;
            unsigned char* dst = smem + rid * LDS_STRIDE + half * 896 + l * 16;
            gld_lds(src, dst);
        }
    }
    __syncthreads();   // drains staging (vmcnt(0)) + publishes LDS

    // ---- accumulators init with bias (co = nh*32 + nt*16 + r) ----
    f32x4 acc[7][2];
    {
        const float bv0 = b2[nh * 32 + r];
        const float bv1 = b2[nh * 32 + 16 + r];
#pragma unroll
        for (int mt = 0; mt < 7; ++mt) {
            acc[mt][0] = (f32x4){bv0, bv0, bv0, bv0};
            acc[mt][1] = (f32x4){bv1, bv1, bv1, bv1};
        }
    }

    // per-lane A base: row (zw+kd)*6 + (yl+kh), x = mt*4 + xg + kw, K-qtr q
    const unsigned char* aBase =
        smem + (zw * 6 + yl) * LDS_STRIDE + xg * 64 + q * 16;

    u32x4 Bs[3][2];
#define B_LOAD(slot, t)                                                        \
    { const char* p_ = wBl + (size_t)(t) * 4096;                               \
      asm volatile("global_load_dwordx4 %0, %2, off\n\t"                       \
                   "global_load_dwordx4 %1, %2, off offset:1024"               \
                   : "=&v"(Bs[slot][0]), "=&v"(Bs[slot][1]) : "v"(p_)); }

    // 2-deep prologue (staging already drained -> vmcnt counting exact)
    B_LOAD(0, 0)
    B_LOAD(1, 1)

    // ---- barrier-free K-loop over 27 taps, fully unrolled ----
#pragma unroll
    for (int tap = 0; tap < 27; ++tap) {
        const int cur = tap % 3;

        if (tap < 25) B_LOAD((tap + 2) % 3, tap + 2)

        // after wait: taps t+1 (and t+2 if issued) remain in flight
        if (tap < 25)       asm volatile("s_waitcnt vmcnt(4)");
        else if (tap == 25) asm volatile("s_waitcnt vmcnt(2)");
        else                asm volatile("s_waitcnt vmcnt(0)");

        asm volatile("" : "+v"(Bs[cur][0]), "+v"(Bs[cur][1]));
        const bf16x8 B0 = __builtin_bit_cast(bf16x8, Bs[cur][0]);
        const bf16x8 B1 = __builtin_bit_cast(bf16x8, Bs[cur][1]);

        const int kd = tap / 9;
        const int kh = (tap - kd * 9) / 3;
        const int kw = tap - kd * 9 - kh * 3;
        const unsigned char* ap = aBase + (kd * 6 + kh) * LDS_STRIDE + kw * 64;

#pragma unroll
        for (int mt = 0; mt < 7; ++mt) {
            const bf16x8 a = *reinterpret_cast<const bf16x8*>(ap + mt * 256);
            acc[mt][0] = __builtin_amdgcn_mfma_f32_16x16x32_bf16(a, B0, acc[mt][0], 0, 0, 0);
            acc[mt][1] = __builtin_amdgcn_mfma_f32_16x16x32_bf16(a, B1, acc[mt][1], 0, 0, 0);
        }
    }
#undef B_LOAD

    // ---- epilogue: lane (r,q): co = nh*32+nt*16+r, y = y0+q, x = mt*4 (+j)
    const int z = z0 + zw;
    float* ob = out + ((size_t)b * 64 + nh * 32 + r) * OUT_CSTR
                    + (size_t)z * 784 + (size_t)(y0 + q) * 28;
#pragma unroll
    for (int mt = 0; mt < 7; ++mt) {
#pragma unroll
        for (int nt = 0; nt < 2; ++nt) {
            const f32x4 v = acc[mt][nt];
            float4 st;
            st.x = fmaxf(v.x, 0.f);
            st.y = fmaxf(v.y, 0.f);
            st.z = fmaxf(v.z, 0.f);
            st.w = fmaxf(v.w, 0.f);
            *reinterpret_cast<float4*>(ob + (size_t)nt * 16 * OUT_CSTR + mt * 4) = st;
        }
    }
}

extern "C" void kernel_launch(void* const* d_in, const int* in_sizes, int n_in,
                              void* d_out, int out_size, void* d_ws, size_t ws_size,
                              hipStream_t stream)
{
    const float* x  = (const float*)d_in[0];
    const float* w1 = (const float*)d_in[1];
    const float* b1 = (const float*)d_in[2];
    const float* w2 = (const float*)d_in[3];
    const float* b2 = (const float*)d_in[4];
    float* out = (float*)d_out;

    u16* wB = (u16*)d_ws;                               // 110,592 B packed weights
    u16* h1 = (u16*)((char*)d_ws + 131072);

    pack_w2<<<27, 256, 0, stream>>>(w2, wB);

    const size_t per_batch = (size_t)H1_BATCH * 2;      // 1,728,000 B
    size_t avail = ws_size > 131072 ? ws_size - 131072 : 0;
    int bchunk = (int)(avail / per_batch);
    if (bchunk < 1)  bchunk = 1;
    if (bchunk > 64) bchunk = 64;

    for (int b0 = 0; b0 < 64; b0 += bchunk) {
        int bc = 64 - b0;
        if (bc > bchunk) bc = bchunk;
        conv1_relu<<<dim3(30, 5, bc), 256, 0, stream>>>(x, w1, b1, h1, b0);
        conv2_mfma<<<dim3(49 * bc), 512, 0, stream>>>(h1, wB, b2, out, b0);
    }
}